// Round 8
// baseline (852.472 us; speedup 1.0000x reference)
//
#include <hip/hip_runtime.h>

#define NN 100000
#define NE 3200000
#define NBUK 196                  // ceil(NN/512) buckets of 512 nodes
#define CAP 18432                 // max edges per bucket (E/NBUK=16327 + slack)
#define NAB 512                   // binning blocks
#define ECHK ((NE + NAB - 1)/NAB) // 6250 edges per binning block

typedef unsigned short u16;
typedef unsigned int u32;
typedef __attribute__((ext_vector_type(8))) short short8v;
typedef __attribute__((ext_vector_type(4))) float f32x4;

__device__ __forceinline__ u16 f2b(float f){
  u32 u = __float_as_uint(f);
  u32 r = (u + 0x7fffu + ((u >> 16) & 1u)) >> 16;
  return (u16)r;
}
__device__ __forceinline__ float b2f(u16 b){
  return __uint_as_float(((u32)b) << 16);
}

// ---------------- misc: weight transposes (fp32->bf16 NxK) + zero counters -------
__global__ void k_misc(const float* __restrict__ W0, const float* __restrict__ W1,
                       const float* __restrict__ W2, const float* __restrict__ Wm1,
                       u16* __restrict__ wt0, u16* __restrict__ wt1,
                       u16* __restrict__ wt2, u16* __restrict__ wtm1,
                       u32* __restrict__ gcntD, u32* __restrict__ gcntS,
                       float* __restrict__ bns, float* __restrict__ bnq){
  int i = blockIdx.x*256 + threadIdx.x;
  if(i < 16384){
    int n = i >> 7, k = i & 127;                  // K=128,N=128
    wt0[i] = f2b(W0[k*128 + n]);
  } else if((i -= 16384) < 32768){
    int n = i >> 7, k = i & 127;                  // K=128,N=256
    wt1[i] = f2b(W1[k*256 + n]);
  } else if((i -= 32768) < 65536){
    int n = i >> 8, k = i & 255;                  // K=256,N=256
    wt2[i] = f2b(W2[k*256 + n]);
  } else if((i -= 65536) < 51200){
    int n = i >> 8, k = i & 255;                  // K=256,N=200
    wtm1[i] = f2b(Wm1[k*200 + n]);
  } else if((i -= 51200) < 512){
    if(i < 256) gcntD[i] = 0; else gcntS[i-256] = 0;
  } else if((i -= 512) < 400){
    if(i < 200) bns[i] = 0.f; else bnq[i-200] = 0.f;
  }
}

// ---------------- binning: scatter edges into node-range buckets ----------------
__global__ __launch_bounds__(256) void k_bin(const int* __restrict__ src,
                      const int* __restrict__ dst,
                      u32* __restrict__ gcntD, u32* __restrict__ gcntS,
                      u32* __restrict__ pairD, u16* __restrict__ keyS){
  __shared__ u32 cntD[NBUK], cntS[NBUK], offD[NBUK], offS[NBUK];
  int t = threadIdx.x, b = blockIdx.x;
  for(int j=t; j<NBUK; j+=256){ cntD[j]=0; cntS[j]=0; }
  __syncthreads();
  int start = b*ECHK, end = min(start + ECHK, NE);
  for(int e = start + t; e < end; e += 256){
    atomicAdd(&cntD[dst[e] >> 9], 1u);
    atomicAdd(&cntS[src[e] >> 9], 1u);
  }
  __syncthreads();
  for(int j=t; j<NBUK; j+=256){
    offD[j] = atomicAdd(&gcntD[j], cntD[j]);
    offS[j] = atomicAdd(&gcntS[j], cntS[j]);
    cntD[j] = 0; cntS[j] = 0;     // reuse as fill
  }
  __syncthreads();
  for(int e = start + t; e < end; e += 256){
    int d = dst[e], s = src[e];
    int bd = d >> 9, bs = s >> 9;
    u32 pd = offD[bd] + atomicAdd(&cntD[bd], 1u);
    u32 ps = offS[bs] + atomicAdd(&cntS[bs], 1u);
    if(pd < CAP) pairD[bd*CAP + pd] = ((u32)s << 9) | (u32)(d & 511);
    if(ps < CAP) keyS[bs*CAP + ps] = (u16)(s & 511);
  }
}

// ---------------- bucket totals -> bucket edge offsets ----------------
__global__ void k_boff(const u32* __restrict__ gcntD, u32* __restrict__ bOffD){
  if(threadIdx.x==0){
    u32 run = 0;
    for(int i=0;i<NBUK;i++){ bOffD[i]=run; run+=gcntD[i]; }
  }
}

// ---------------- per-dst-bucket: degi, nd, rowp, CSR fill ----------------
__global__ __launch_bounds__(256) void k_bucket_dst(
    const u32* __restrict__ pairD, const u32* __restrict__ gcntD,
    const u32* __restrict__ bOffD, int* __restrict__ degi,
    float* __restrict__ nd, int* __restrict__ rowp, int* __restrict__ csr){
  __shared__ u32 hist[512], excl[512], fill[512], tsum[256];
  int t = threadIdx.x, b = blockIdx.x;
  int base = b << 9;
  hist[t] = 0; hist[t+256] = 0; fill[t] = 0; fill[t+256] = 0;
  __syncthreads();
  int nD = gcntD[b];
  const u32* pp = pairD + (size_t)b*CAP;
  for(int i=t; i<nD; i+=256) atomicAdd(&hist[pp[i] & 511], 1u);
  __syncthreads();
  u32 a0 = hist[2*t], a1 = hist[2*t+1];
  tsum[t] = a0 + a1;
  __syncthreads();
  for(int off=1; off<256; off<<=1){
    u32 v = (t>=off) ? tsum[t-off] : 0;
    __syncthreads();
    tsum[t] += v;
    __syncthreads();
  }
  u32 texc = tsum[t] - (a0 + a1);
  excl[2*t] = texc; excl[2*t+1] = texc + a0;
  __syncthreads();
  u32 bo = bOffD[b];
  #pragma unroll
  for(int j=0;j<2;j++){
    int local = t + j*256;
    int v = base + local;
    if(v < NN){
      int cnt = (int)hist[local];
      degi[v] = cnt + 1;                 // + self-loop
      nd[v] = rsqrtf((float)(cnt + 1));
      rowp[v] = (int)(bo + excl[local]);
    }
  }
  __syncthreads();
  for(int i=t; i<nD; i+=256){
    u32 w = pp[i];
    int local = w & 511;
    u32 pos = bo + excl[local] + atomicAdd(&fill[local], 1u);
    csr[pos] = (int)(w >> 9);
  }
}

// ---------------- per-src-bucket: ns ----------------
__global__ __launch_bounds__(256) void k_bucket_src(
    const u16* __restrict__ keyS, const u32* __restrict__ gcntS,
    float* __restrict__ ns){
  __shared__ u32 hist[512];
  int t = threadIdx.x, b = blockIdx.x;
  hist[t] = 0; hist[t+256] = 0;
  __syncthreads();
  int nS = gcntS[b];
  const u16* kp = keyS + (size_t)b*CAP;
  for(int i=t; i<nS; i+=256) atomicAdd(&hist[kp[i]], 1u);
  __syncthreads();
  #pragma unroll
  for(int j=0;j<2;j++){
    int local = t + j*256;
    int v = (b << 9) + local;
    if(v < NN) ns[v] = rsqrtf((float)(hist[local] + 1));
  }
}

// ---------------- convert features*ns -> bf16 ----------------
__global__ void k_cvt(const float* __restrict__ f, const float* __restrict__ ns,
                      u16* __restrict__ out){
  int i = blockIdx.x*256 + threadIdx.x;    // groups of 4 elems, 32 groups/row
  if(i >= NN*32) return;
  int row = i >> 5;
  float nsv = ns[row];
  float4 v = *(const float4*)(f + (size_t)i*4);
  u32 w0 = (u32)f2b(v.x*nsv) | ((u32)f2b(v.y*nsv) << 16);
  u32 w1 = (u32)f2b(v.z*nsv) | ((u32)f2b(v.w*nsv) << 16);
  *(uint2*)(out + (size_t)i*4) = make_uint2(w0, w1);
}

// ---------------- SpMM: EP=8 groups of 8 lanes, register double-buffer ----------
template<int DIM>
__global__ void k_spmm8(const u16* __restrict__ h, const int* __restrict__ rowp,
                        const int* __restrict__ degi, const int* __restrict__ csr,
                        const float* __restrict__ nd, u16* __restrict__ out){
  constexpr int EP = 8, G = 8;
  constexpr int NV = DIM/(G*8);      // uint4 per lane per row (2 or 4)
  int w = (blockIdx.x*blockDim.x + threadIdx.x) >> 6;
  int lane = threadIdx.x & 63;
  if(w >= NN) return;
  int g = lane >> 3, gl = lane & 7;
  const uint4* hv = (const uint4*)h;  // DIM/8 uint4 per row
  float acc[NV*8];
  #pragma unroll
  for(int i=0;i<NV*8;i++) acc[i]=0.f;

  int start = rowp[w];
  int vcnt = degi[w];                 // cnt + 1 (self first)

  uint4 cur[NV];
  int k = g;
  if(k < vcnt){
    int n0 = (k == 0) ? w : csr[start + k - 1];
    #pragma unroll
    for(int v4=0; v4<NV; v4++) cur[v4] = hv[(size_t)n0*(DIM/8) + gl*NV + v4];

    int kn = k + EP;
    int nn = (kn < vcnt) ? csr[start + kn - 1] : 0;   // csr prefetch

    while(true){
      bool more = (kn < vcnt);
      uint4 nxt[NV];
      if(more){
        #pragma unroll
        for(int v4=0; v4<NV; v4++) nxt[v4] = hv[(size_t)nn*(DIM/8) + gl*NV + v4];
      }
      int k2 = kn + EP;
      if(k2 < vcnt) nn = csr[start + k2 - 1];          // csr prefetch 2 ahead
      #pragma unroll
      for(int v4=0; v4<NV; v4++){
        u32 wd[4] = {cur[v4].x, cur[v4].y, cur[v4].z, cur[v4].w};
        #pragma unroll
        for(int i=0;i<4;i++){
          acc[v4*8 + 2*i]   += __uint_as_float(wd[i] << 16);
          acc[v4*8 + 2*i+1] += __uint_as_float(wd[i] & 0xffff0000u);
        }
      }
      if(!more) break;
      #pragma unroll
      for(int v4=0; v4<NV; v4++) cur[v4] = nxt[v4];
      kn = k2;
    }
  }

  #pragma unroll
  for(int i=0;i<NV*8;i++){
    acc[i] += __shfl_xor(acc[i], 8);
    acc[i] += __shfl_xor(acc[i], 16);
    acc[i] += __shfl_xor(acc[i], 32);
  }
  if(g == 0){
    float ndv = nd[w];
    #pragma unroll
    for(int v4=0; v4<NV; v4++){
      u32 o[4];
      #pragma unroll
      for(int i=0;i<4;i++){
        o[i] = (u32)f2b(acc[v4*8+2*i]*ndv) | ((u32)f2b(acc[v4*8+2*i+1]*ndv) << 16);
      }
      *(uint4*)(out + (size_t)w*DIM + (gl*NV + v4)*8) = make_uint4(o[0],o[1],o[2],o[3]);
    }
  }
}

// ---------------- barrier-free streaming MFMA GEMM ----------------
// A: M x KK bf16 row-major (read direct from global, per-fragment).
// Bt: N x KK bf16 (staged whole into LDS once, (row&7) XOR-swizzled 16B chunks).
// OUTMODE 0: bf16 out * ns[row]; 1: bf16 out; 2: fp32 out + BN col sums.
template<int OUTMODE, int KK>
__global__ __launch_bounds__(256) void k_gemm2(
    const u16* __restrict__ A, const u16* __restrict__ Bt,
    const float* __restrict__ bias, const float* __restrict__ ns,
    u16* __restrict__ outb, float* __restrict__ outf,
    float* __restrict__ bns, float* __restrict__ bnq,
    int M, int Nn)
{
  constexpr int NCH = KK/8;              // 16B chunks per row
  __shared__ u16 Bs[128*KK];
  int t = threadIdx.x;
  int wave = t >> 6, lane = t & 63;
  int l15 = lane & 15, l4 = lane >> 4;
  int wr = (wave >> 1)*64, wc = (wave & 1)*64;
  int row0 = blockIdx.y*128, col0 = blockIdx.x*128;

  // stage whole B tile once: thread t -> row t>>1, half (t&1)
  {
    int r = t >> 1;
    int cbase = (t & 1)*(NCH/2);
    int sw = r & 7;
    bool valid = (col0 + r) < Nn;
    const uint4* gp = (const uint4*)(Bt + (size_t)(col0 + r)*KK);
    uint4* lp = (uint4*)&Bs[r*KK];
    #pragma unroll
    for(int j=0;j<NCH/2;j++){
      int c = cbase + j;
      uint4 v = valid ? gp[c] : make_uint4(0,0,0,0);
      lp[c ^ sw] = v;
    }
  }
  __syncthreads();

  f32x4 acc[4][4];
  #pragma unroll
  for(int m=0;m<4;m++)
    #pragma unroll
    for(int n=0;n<4;n++) acc[m][n] = (f32x4)(0.f);

  #pragma unroll
  for(int k0=0; k0<KK; k0+=64){
    short8v af[4][2], bg[4][2];
    #pragma unroll
    for(int m=0;m<4;m++){
      const u16* ap = A + (size_t)(row0 + wr + m*16 + l15)*KK + k0 + l4*8;
      af[m][0] = *(const short8v*)ap;
      af[m][1] = *(const short8v*)(ap + 32);
    }
    #pragma unroll
    for(int n=0;n<4;n++){
      int r = wc + n*16 + l15;
      int sw = r & 7;
      int base = r*NCH + (k0>>3);
      bg[n][0] = *(const short8v*)&Bs[(base + ((l4    ) ^ sw))*8];
      bg[n][1] = *(const short8v*)&Bs[(base + ((l4 + 4) ^ sw))*8];
    }
    #pragma unroll
    for(int ks=0; ks<2; ks++)
      #pragma unroll
      for(int m=0;m<4;m++)
        #pragma unroll
        for(int n=0;n<4;n++)
          acc[m][n] = __builtin_amdgcn_mfma_f32_16x16x32_bf16(af[m][ks], bg[n][ks], acc[m][n], 0, 0, 0);
  }

  float nsv[4][4];
  if(OUTMODE == 0){
    #pragma unroll
    for(int m=0;m<4;m++)
      #pragma unroll
      for(int r=0;r<4;r++){
        int gr = row0 + wr + m*16 + l4*4 + r;
        nsv[m][r] = (gr < M) ? ns[gr] : 0.f;
      }
  }
  #pragma unroll
  for(int n=0;n<4;n++){
    int gc = col0 + wc + n*16 + l15;
    float bv = (gc < Nn) ? bias[gc] : 0.f;
    float s = 0.f, q = 0.f;
    #pragma unroll
    for(int m=0;m<4;m++){
      #pragma unroll
      for(int r=0;r<4;r++){
        int gr = row0 + wr + m*16 + l4*4 + r;
        bool ok = (gr < M) && (gc < Nn);
        float v = ok ? fmaxf(acc[m][n][r] + bv, 0.f) : 0.f;
        if(ok){
          if(OUTMODE == 0)      outb[(size_t)gr*Nn + gc] = f2b(v * nsv[m][r]);
          else if(OUTMODE == 1) outb[(size_t)gr*Nn + gc] = f2b(v);
          else                  outf[(size_t)gr*Nn + gc] = v;
        }
        if(OUTMODE == 2){ s += v; q += v*v; }
      }
    }
    if(OUTMODE == 2){
      s += __shfl_xor(s, 16); s += __shfl_xor(s, 32);
      q += __shfl_xor(q, 16); q += __shfl_xor(q, 32);
      if(l4 == 0 && gc < Nn){ atomicAdd(&bns[gc], s); atomicAdd(&bnq[gc], q); }
    }
  }
}

// ---------------- batchnorm finalize + fused final linear ----------------
__global__ void k_bn2(const float* __restrict__ bns, const float* __restrict__ bnq,
                      const float* __restrict__ gamma, const float* __restrict__ beta,
                      const float* __restrict__ Wm2, const float* __restrict__ bm2,
                      float* __restrict__ w2a, float* __restrict__ cc2){
  __shared__ float c0s[200];
  int t = threadIdx.x;
  if(t<200){
    float mu  = bns[t] * (1.0f/NN);
    float var = bnq[t] * (1.0f/NN) - mu*mu;
    float a   = rsqrtf(var + 1e-5f) * gamma[t];
    w2a[t*2+0] = a*Wm2[t*2+0];
    w2a[t*2+1] = a*Wm2[t*2+1];
    c0s[t] = beta[t] - mu*a;
  }
  __syncthreads();
  if(t<2){
    float cst = bm2[t];
    for(int k=0;k<200;k++) cst += c0s[k]*Wm2[k*2+t];
    cc2[t] = cst;
  }
}

__global__ void k_final(const float* __restrict__ z, const float* __restrict__ w2a,
                        const float* __restrict__ cc2, float* __restrict__ out){
  int lane = threadIdx.x & 63;
  int gw = (blockIdx.x*blockDim.x + threadIdx.x) >> 6;
  if(gw >= NN) return;
  const float* zr = z + (size_t)gw*200;
  float p0=0.f, p1=0.f;
  #pragma unroll
  for(int i=0;i<4;i++){
    int c = lane + i*64;
    if(c<200){ float x=zr[c]; p0 += x*w2a[c*2+0]; p1 += x*w2a[c*2+1]; }
  }
  for(int off=32; off>0; off>>=1){
    p0 += __shfl_down(p0, off);
    p1 += __shfl_down(p1, off);
  }
  if(lane==0){ out[gw*2+0] = p0 + cc2[0]; out[gw*2+1] = p1 + cc2[1]; }
}

// ---------------- launch ----------------
extern "C" void kernel_launch(void* const* d_in, const int* in_sizes, int n_in,
                              void* d_out, int out_size, void* d_ws, size_t ws_size,
                              hipStream_t stream) {
  const float* features = (const float*)d_in[0];
  const int*   src = (const int*)d_in[1];
  const int*   dst = (const int*)d_in[2];
  const float* W0  = (const float*)d_in[3];
  const float* b0  = (const float*)d_in[4];
  const float* W1  = (const float*)d_in[5];
  const float* b1  = (const float*)d_in[6];
  const float* W2  = (const float*)d_in[7];
  const float* b2  = (const float*)d_in[8];
  const float* Wm1 = (const float*)d_in[9];
  const float* bm1 = (const float*)d_in[10];
  const float* gamma = (const float*)d_in[11];
  const float* beta  = (const float*)d_in[12];
  const float* Wm2 = (const float*)d_in[13];
  const float* bm2 = (const float*)d_in[14];
  float* out = (float*)d_out;

  char* p = (char*)d_ws;
  auto alloc = [&](size_t bytes)->void*{
    void* r = (void*)p; p += (bytes + 255) & ~(size_t)255; return r;
  };
  u16*   X    = (u16*)alloc((size_t)NN*256*2);
  u16*   Y    = (u16*)alloc((size_t)NN*256*2);
  float* z    = (float*)alloc((size_t)NN*200*4);     // 80 MB, dead until MLP GEMM
  int*   csr  = (int*)alloc((size_t)NE*4);
  int*   rowp = (int*)alloc((size_t)NN*4);
  int*   degi = (int*)alloc((size_t)NN*4);
  float* ns   = (float*)alloc((size_t)NN*4);
  float* nd   = (float*)alloc((size_t)NN*4);
  u32*   gcntD = (u32*)alloc(256*4);
  u32*   gcntS = (u32*)alloc(256*4);
  u32*   bOffD = (u32*)alloc(256*4);
  float* bns  = (float*)alloc(200*4);
  float* bnq  = (float*)alloc(200*4);
  float* w2a  = (float*)alloc(400*4);
  float* cc2  = (float*)alloc(2*4);
  u16*   wt0  = (u16*)alloc((size_t)128*128*2);
  u16*   wt1  = (u16*)alloc((size_t)256*128*2);
  u16*   wt2  = (u16*)alloc((size_t)256*256*2);
  u16*   wtm1 = (u16*)alloc((size_t)256*256*2);      // padded so OOB B-rows stay in-alloc
  // bucket scratch aliased onto z (lifetimes disjoint): pairD 14.5MB, keyS 7.3MB
  u32*   pairD = (u32*)z;
  u16*   keyS  = (u16*)((char*)z + (size_t)32*1024*1024);

  // prep: transposes + zero counters, then binned counting sort
  k_misc<<<(16384+32768+65536+51200+512+400 + 255)/256, 256, 0, stream>>>(
      W0, W1, W2, Wm1, wt0, wt1, wt2, wtm1, gcntD, gcntS, bns, bnq);
  k_bin<<<NAB, 256, 0, stream>>>(src, dst, gcntD, gcntS, pairD, keyS);
  k_boff<<<1, 64, 0, stream>>>(gcntD, bOffD);
  k_bucket_dst<<<NBUK, 256, 0, stream>>>(pairD, gcntD, bOffD, degi, nd, rowp, csr);
  k_bucket_src<<<NBUK, 256, 0, stream>>>(keyS, gcntS, ns);

  // features * ns -> bf16
  k_cvt<<<(NN*32 + 255)/256, 256, 0, stream>>>(features, ns, X);

  int sblk = (NN + 3)/4;             // 1 wave per node
  int gblk = (NN + 127)/128;         // GEMM row blocks

  // layer 0
  k_spmm8<128><<<sblk, 256, 0, stream>>>(X, rowp, degi, csr, nd, Y);
  k_gemm2<0,128><<<dim3(1,gblk), 256, 0, stream>>>(Y, wt0, b0, ns, X, nullptr, nullptr, nullptr, NN, 128);
  // layer 1
  k_spmm8<128><<<sblk, 256, 0, stream>>>(X, rowp, degi, csr, nd, Y);
  k_gemm2<0,128><<<dim3(2,gblk), 256, 0, stream>>>(Y, wt1, b1, ns, X, nullptr, nullptr, nullptr, NN, 256);
  // layer 2
  k_spmm8<256><<<sblk, 256, 0, stream>>>(X, rowp, degi, csr, nd, Y);
  k_gemm2<1,256><<<dim3(2,gblk), 256, 0, stream>>>(Y, wt2, b2, nullptr, X, nullptr, nullptr, nullptr, NN, 256);
  // MLP hidden: z = relu(h3 @ Wm1 + bm1) + fused BN column stats
  k_gemm2<2,256><<<dim3(2,gblk), 256, 0, stream>>>(X, wtm1, bm1, nullptr, nullptr, z, bns, bnq, NN, 200);

  // batchnorm finalize + final linear
  k_bn2<<<1, 256, 0, stream>>>(bns, bnq, gamma, beta, Wm2, bm2, w2a, cc2);
  k_final<<<sblk, 256, 0, stream>>>(z, w2a, cc2, out);
}

// Round 10
// 766.508 us; speedup vs baseline: 1.1121x; 1.1121x over previous
//
#include <hip/hip_runtime.h>

#define NN 100000
#define NE 3200000
#define NBUK 196                  // ceil(NN/512) buckets of 512 nodes
#define CAP 18432                 // max edges per bucket (E/NBUK=16327 + slack)
#define NAB 512                   // binning blocks
#define ECHK ((NE + NAB - 1)/NAB) // 6250 edges per binning block

typedef unsigned short u16;
typedef unsigned int u32;
typedef __attribute__((ext_vector_type(8))) short short8v;
typedef __attribute__((ext_vector_type(4))) float f32x4;

__device__ __forceinline__ u16 f2b(float f){
  u32 u = __float_as_uint(f);
  u32 r = (u + 0x7fffu + ((u >> 16) & 1u)) >> 16;
  return (u16)r;
}
__device__ __forceinline__ float b2f(u16 b){
  return __uint_as_float(((u32)b) << 16);
}

// ---------------- misc: weight transposes (fp32->bf16 NxK) + zero counters -------
__global__ void k_misc(const float* __restrict__ W0, const float* __restrict__ W1,
                       const float* __restrict__ W2, const float* __restrict__ Wm1,
                       u16* __restrict__ wt0, u16* __restrict__ wt1,
                       u16* __restrict__ wt2, u16* __restrict__ wtm1,
                       u32* __restrict__ gcntD, u32* __restrict__ gcntS,
                       float* __restrict__ bns, float* __restrict__ bnq){
  int i = blockIdx.x*256 + threadIdx.x;
  if(i < 16384){
    int n = i >> 7, k = i & 127;                  // K=128,N=128
    wt0[i] = f2b(W0[k*128 + n]);
  } else if((i -= 16384) < 32768){
    int n = i >> 7, k = i & 127;                  // K=128,N=256
    wt1[i] = f2b(W1[k*256 + n]);
  } else if((i -= 32768) < 65536){
    int n = i >> 8, k = i & 255;                  // K=256,N=256
    wt2[i] = f2b(W2[k*256 + n]);
  } else if((i -= 65536) < 51200){
    int n = i >> 8, k = i & 255;                  // K=256,N=200
    wtm1[i] = f2b(Wm1[k*200 + n]);
  } else if((i -= 51200) < 512){
    if(i < 256) gcntD[i] = 0; else gcntS[i-256] = 0;
  } else if((i -= 512) < 400){
    if(i < 200) bns[i] = 0.f; else bnq[i-200] = 0.f;
  }
}

// ---------------- binning: scatter edges into node-range buckets ----------------
__global__ __launch_bounds__(256) void k_bin(const int* __restrict__ src,
                      const int* __restrict__ dst,
                      u32* __restrict__ gcntD, u32* __restrict__ gcntS,
                      u32* __restrict__ pairD, u16* __restrict__ keyS){
  __shared__ u32 cntD[NBUK], cntS[NBUK], offD[NBUK], offS[NBUK];
  int t = threadIdx.x, b = blockIdx.x;
  for(int j=t; j<NBUK; j+=256){ cntD[j]=0; cntS[j]=0; }
  __syncthreads();
  int start = b*ECHK, end = min(start + ECHK, NE);
  for(int e = start + t; e < end; e += 256){
    atomicAdd(&cntD[dst[e] >> 9], 1u);
    atomicAdd(&cntS[src[e] >> 9], 1u);
  }
  __syncthreads();
  for(int j=t; j<NBUK; j+=256){
    offD[j] = atomicAdd(&gcntD[j], cntD[j]);
    offS[j] = atomicAdd(&gcntS[j], cntS[j]);
    cntD[j] = 0; cntS[j] = 0;     // reuse as fill
  }
  __syncthreads();
  for(int e = start + t; e < end; e += 256){
    int d = dst[e], s = src[e];
    int bd = d >> 9, bs = s >> 9;
    u32 pd = offD[bd] + atomicAdd(&cntD[bd], 1u);
    u32 ps = offS[bs] + atomicAdd(&cntS[bs], 1u);
    if(pd < CAP) pairD[bd*CAP + pd] = ((u32)s << 9) | (u32)(d & 511);
    if(ps < CAP) keyS[bs*CAP + ps] = (u16)(s & 511);
  }
}

// ---------------- bucket totals -> bucket edge offsets ----------------
__global__ void k_boff(const u32* __restrict__ gcntD, u32* __restrict__ bOffD){
  if(threadIdx.x==0){
    u32 run = 0;
    for(int i=0;i<NBUK;i++){ bOffD[i]=run; run+=gcntD[i]; }
  }
}

// ---------------- per-dst-bucket: degi, nd, rowp, CSR fill ----------------
__global__ __launch_bounds__(256) void k_bucket_dst(
    const u32* __restrict__ pairD, const u32* __restrict__ gcntD,
    const u32* __restrict__ bOffD, int* __restrict__ degi,
    float* __restrict__ nd, int* __restrict__ rowp, int* __restrict__ csr){
  __shared__ u32 hist[512], excl[512], fill[512], tsum[256];
  int t = threadIdx.x, b = blockIdx.x;
  int base = b << 9;
  hist[t] = 0; hist[t+256] = 0; fill[t] = 0; fill[t+256] = 0;
  __syncthreads();
  int nD = gcntD[b];
  const u32* pp = pairD + (size_t)b*CAP;
  for(int i=t; i<nD; i+=256) atomicAdd(&hist[pp[i] & 511], 1u);
  __syncthreads();
  u32 a0 = hist[2*t], a1 = hist[2*t+1];
  tsum[t] = a0 + a1;
  __syncthreads();
  for(int off=1; off<256; off<<=1){
    u32 v = (t>=off) ? tsum[t-off] : 0;
    __syncthreads();
    tsum[t] += v;
    __syncthreads();
  }
  u32 texc = tsum[t] - (a0 + a1);
  excl[2*t] = texc; excl[2*t+1] = texc + a0;
  __syncthreads();
  u32 bo = bOffD[b];
  #pragma unroll
  for(int j=0;j<2;j++){
    int local = t + j*256;
    int v = base + local;
    if(v < NN){
      int cnt = (int)hist[local];
      degi[v] = cnt + 1;                 // + self-loop
      nd[v] = rsqrtf((float)(cnt + 1));
      rowp[v] = (int)(bo + excl[local]);
    }
  }
  __syncthreads();
  for(int i=t; i<nD; i+=256){
    u32 w = pp[i];
    int local = w & 511;
    u32 pos = bo + excl[local] + atomicAdd(&fill[local], 1u);
    csr[pos] = (int)(w >> 9);
  }
}

// ---------------- per-src-bucket: ns ----------------
__global__ __launch_bounds__(256) void k_bucket_src(
    const u16* __restrict__ keyS, const u32* __restrict__ gcntS,
    float* __restrict__ ns){
  __shared__ u32 hist[512];
  int t = threadIdx.x, b = blockIdx.x;
  hist[t] = 0; hist[t+256] = 0;
  __syncthreads();
  int nS = gcntS[b];
  const u16* kp = keyS + (size_t)b*CAP;
  for(int i=t; i<nS; i+=256) atomicAdd(&hist[kp[i]], 1u);
  __syncthreads();
  #pragma unroll
  for(int j=0;j<2;j++){
    int local = t + j*256;
    int v = (b << 9) + local;
    if(v < NN) ns[v] = rsqrtf((float)(hist[local] + 1));
  }
}

// ---------------- convert features*ns -> bf16 ----------------
__global__ void k_cvt(const float* __restrict__ f, const float* __restrict__ ns,
                      u16* __restrict__ out){
  int i = blockIdx.x*256 + threadIdx.x;    // groups of 4 elems, 32 groups/row
  if(i >= NN*32) return;
  int row = i >> 5;
  float nsv = ns[row];
  float4 v = *(const float4*)(f + (size_t)i*4);
  u32 w0 = (u32)f2b(v.x*nsv) | ((u32)f2b(v.y*nsv) << 16);
  u32 w1 = (u32)f2b(v.z*nsv) | ((u32)f2b(v.w*nsv) << 16);
  *(uint2*)(out + (size_t)i*4) = make_uint2(w0, w1);
}

// ---------------- SpMM: EP=8 groups of 8 lanes, register double-buffer ----------
template<int DIM>
__global__ void k_spmm8(const u16* __restrict__ h, const int* __restrict__ rowp,
                        const int* __restrict__ degi, const int* __restrict__ csr,
                        const float* __restrict__ nd, u16* __restrict__ out){
  constexpr int EP = 8, G = 8;
  constexpr int NV = DIM/(G*8);      // uint4 per lane per row (2 or 4)
  int w = (blockIdx.x*blockDim.x + threadIdx.x) >> 6;
  int lane = threadIdx.x & 63;
  if(w >= NN) return;
  int g = lane >> 3, gl = lane & 7;
  const uint4* hv = (const uint4*)h;  // DIM/8 uint4 per row
  float acc[NV*8];
  #pragma unroll
  for(int i=0;i<NV*8;i++) acc[i]=0.f;

  int start = rowp[w];
  int vcnt = degi[w];                 // cnt + 1 (self first)

  uint4 cur[NV];
  int k = g;
  if(k < vcnt){
    int n0 = (k == 0) ? w : csr[start + k - 1];
    #pragma unroll
    for(int v4=0; v4<NV; v4++) cur[v4] = hv[(size_t)n0*(DIM/8) + gl*NV + v4];

    int kn = k + EP;
    int nn = (kn < vcnt) ? csr[start + kn - 1] : 0;   // csr prefetch

    while(true){
      bool more = (kn < vcnt);
      uint4 nxt[NV];
      if(more){
        #pragma unroll
        for(int v4=0; v4<NV; v4++) nxt[v4] = hv[(size_t)nn*(DIM/8) + gl*NV + v4];
      }
      int k2 = kn + EP;
      if(k2 < vcnt) nn = csr[start + k2 - 1];          // csr prefetch 2 ahead
      #pragma unroll
      for(int v4=0; v4<NV; v4++){
        u32 wd[4] = {cur[v4].x, cur[v4].y, cur[v4].z, cur[v4].w};
        #pragma unroll
        for(int i=0;i<4;i++){
          acc[v4*8 + 2*i]   += __uint_as_float(wd[i] << 16);
          acc[v4*8 + 2*i+1] += __uint_as_float(wd[i] & 0xffff0000u);
        }
      }
      if(!more) break;
      #pragma unroll
      for(int v4=0; v4<NV; v4++) cur[v4] = nxt[v4];
      kn = k2;
    }
  }

  #pragma unroll
  for(int i=0;i<NV*8;i++){
    acc[i] += __shfl_xor(acc[i], 8);
    acc[i] += __shfl_xor(acc[i], 16);
    acc[i] += __shfl_xor(acc[i], 32);
  }
  if(g == 0){
    float ndv = nd[w];
    #pragma unroll
    for(int v4=0; v4<NV; v4++){
      u32 o[4];
      #pragma unroll
      for(int i=0;i<4;i++){
        o[i] = (u32)f2b(acc[v4*8+2*i]*ndv) | ((u32)f2b(acc[v4*8+2*i+1]*ndv) << 16);
      }
      *(uint4*)(out + (size_t)w*DIM + (gl*NV + v4)*8) = make_uint4(o[0],o[1],o[2],o[3]);
    }
  }
}

// ---------------- 8-wave MFMA GEMM: tile 128 rows x 256 cols (full N) ----------
// A: M x KK bf16 row-major. Bt: N x KK bf16 row-major. fp32 accum.
// OUTMODE 0: bf16 out * ns[row]; 1: bf16 out; 2: bf16 out + BN col sums.
template<int OUTMODE, int KK>
__global__ __launch_bounds__(512) void k_gemm8(
    const u16* __restrict__ A, const u16* __restrict__ Bt,
    const float* __restrict__ bias, const float* __restrict__ ns,
    u16* __restrict__ outb,
    float* __restrict__ bns, float* __restrict__ bnq,
    int M, int Nn)
{
  __shared__ u16 As[128*32];
  __shared__ u16 Bs[256*32];
  int t = threadIdx.x;
  int wave = t >> 6, lane = t & 63;
  int l15 = lane & 15, l4 = lane >> 4;
  int wr = (wave >> 2)*64, wc = (wave & 3)*64;
  int row0 = blockIdx.y*128;

  f32x4 acc[4][4];
  #pragma unroll
  for(int m=0;m<4;m++)
    #pragma unroll
    for(int n=0;n<4;n++) acc[m][n] = (f32x4)(0.f);

  // staging maps
  int ar = t >> 2, ac = t & 3;             // A: 4 threads/row, 1 chunk each
  int swA = (ar >> 1) & 3;
  int br = t >> 1, bc0 = (t & 1)*2;        // B: 2 threads/row, 2 chunks each
  int swB = (br >> 1) & 3;
  bool avalid = (row0 + ar) < M;
  bool bvalid = br < Nn;
  const u16* Ap = A  + (size_t)(row0 + ar)*KK + ac*8;
  const u16* Bp = Bt + (size_t)br*KK + bc0*8;

  #pragma unroll
  for(int k0 = 0; k0 < KK; k0 += 32){
    uint4 va = make_uint4(0,0,0,0), vb0 = va, vb1 = va;
    if(avalid) va = *(const uint4*)(Ap + k0);
    if(bvalid){ vb0 = *(const uint4*)(Bp + k0); vb1 = *(const uint4*)(Bp + k0 + 8); }
    __syncthreads();
    *(uint4*)&As[ar*32 + (ac ^ swA)*8] = va;
    *(uint4*)&Bs[br*32 + (bc0 ^ swB)*8] = vb0;
    *(uint4*)&Bs[br*32 + ((bc0+1) ^ swB)*8] = vb1;
    __syncthreads();

    short8v af[4], bg[4];
    #pragma unroll
    for(int m=0;m<4;m++){
      int r = wr + m*16 + l15;
      int kc = l4 ^ ((r >> 1) & 3);
      af[m] = *(const short8v*)&As[r*32 + kc*8];
    }
    #pragma unroll
    for(int n=0;n<4;n++){
      int r = wc + n*16 + l15;
      int kc = l4 ^ ((r >> 1) & 3);
      bg[n] = *(const short8v*)&Bs[r*32 + kc*8];
    }
    #pragma unroll
    for(int m=0;m<4;m++)
      #pragma unroll
      for(int n=0;n<4;n++)
        acc[m][n] = __builtin_amdgcn_mfma_f32_16x16x32_bf16(af[m], bg[n], acc[m][n], 0, 0, 0);
  }

  float nsv[4][4];
  if(OUTMODE == 0){
    #pragma unroll
    for(int m=0;m<4;m++)
      #pragma unroll
      for(int r=0;r<4;r++){
        int gr = row0 + wr + m*16 + l4*4 + r;
        nsv[m][r] = (gr < M) ? ns[gr] : 0.f;
      }
  }
  #pragma unroll
  for(int n=0;n<4;n++){
    int gc = wc + n*16 + l15;
    float bv = (gc < Nn) ? bias[gc] : 0.f;
    float s = 0.f, q = 0.f;
    #pragma unroll
    for(int m=0;m<4;m++){
      #pragma unroll
      for(int r=0;r<4;r++){
        int gr = row0 + wr + m*16 + l4*4 + r;
        bool ok = (gr < M) && (gc < Nn);
        float v = ok ? fmaxf(acc[m][n][r] + bv, 0.f) : 0.f;
        if(ok){
          if(OUTMODE == 0) outb[(size_t)gr*Nn + gc] = f2b(v * nsv[m][r]);
          else             outb[(size_t)gr*Nn + gc] = f2b(v);
        }
        if(OUTMODE == 2){ s += v; q += v*v; }
      }
    }
    if(OUTMODE == 2){
      s += __shfl_xor(s, 16); s += __shfl_xor(s, 32);
      q += __shfl_xor(q, 16); q += __shfl_xor(q, 32);
      if(l4 == 0 && gc < Nn){ atomicAdd(&bns[gc], s); atomicAdd(&bnq[gc], q); }
    }
  }
}

// ---------------- batchnorm finalize + fused final linear ----------------
__global__ void k_bn2(const float* __restrict__ bns, const float* __restrict__ bnq,
                      const float* __restrict__ gamma, const float* __restrict__ beta,
                      const float* __restrict__ Wm2, const float* __restrict__ bm2,
                      float* __restrict__ w2a, float* __restrict__ cc2){
  __shared__ float c0s[200];
  int t = threadIdx.x;
  if(t<200){
    float mu  = bns[t] * (1.0f/NN);
    float var = bnq[t] * (1.0f/NN) - mu*mu;
    float a   = rsqrtf(var + 1e-5f) * gamma[t];
    w2a[t*2+0] = a*Wm2[t*2+0];
    w2a[t*2+1] = a*Wm2[t*2+1];
    c0s[t] = beta[t] - mu*a;
  }
  __syncthreads();
  if(t<2){
    float cst = bm2[t];
    for(int k=0;k<200;k++) cst += c0s[k]*Wm2[k*2+t];
    cc2[t] = cst;
  }
}

// z is bf16 rows of 200 (100 u32 words)
__global__ void k_final(const u16* __restrict__ z, const float* __restrict__ w2a,
                        const float* __restrict__ cc2, float* __restrict__ out){
  int lane = threadIdx.x & 63;
  int gw = (blockIdx.x*blockDim.x + threadIdx.x) >> 6;
  if(gw >= NN) return;
  const u32* zr = (const u32*)(z + (size_t)gw*200);
  float p0=0.f, p1=0.f;
  #pragma unroll
  for(int i=0;i<2;i++){
    int wd = lane + i*64;
    if(wd < 100){
      u32 v = zr[wd];
      float x0 = __uint_as_float(v << 16);
      float x1 = __uint_as_float(v & 0xffff0000u);
      int e = wd*2;
      p0 += x0*w2a[e*2+0] + x1*w2a[e*2+2];
      p1 += x0*w2a[e*2+1] + x1*w2a[e*2+3];
    }
  }
  for(int off=32; off>0; off>>=1){
    p0 += __shfl_down(p0, off);
    p1 += __shfl_down(p1, off);
  }
  if(lane==0){ out[gw*2+0] = p0 + cc2[0]; out[gw*2+1] = p1 + cc2[1]; }
}

// ---------------- launch ----------------
extern "C" void kernel_launch(void* const* d_in, const int* in_sizes, int n_in,
                              void* d_out, int out_size, void* d_ws, size_t ws_size,
                              hipStream_t stream) {
  const float* features = (const float*)d_in[0];
  const int*   src = (const int*)d_in[1];
  const int*   dst = (const int*)d_in[2];
  const float* W0  = (const float*)d_in[3];
  const float* b0  = (const float*)d_in[4];
  const float* W1  = (const float*)d_in[5];
  const float* b1  = (const float*)d_in[6];
  const float* W2  = (const float*)d_in[7];
  const float* b2  = (const float*)d_in[8];
  const float* Wm1 = (const float*)d_in[9];
  const float* bm1 = (const float*)d_in[10];
  const float* gamma = (const float*)d_in[11];
  const float* beta  = (const float*)d_in[12];
  const float* Wm2 = (const float*)d_in[13];
  const float* bm2 = (const float*)d_in[14];
  float* out = (float*)d_out;

  char* p = (char*)d_ws;
  auto alloc = [&](size_t bytes)->void*{
    void* r = (void*)p; p += (bytes + 255) & ~(size_t)255; return r;
  };
  u16*   X    = (u16*)alloc((size_t)NN*256*2);
  u16*   Y    = (u16*)alloc((size_t)NN*256*2);
  u16*   zb   = (u16*)alloc((size_t)NN*200*2);       // 38.1 MB bf16 z, dead until MLP GEMM
  int*   csr  = (int*)alloc((size_t)NE*4);
  int*   rowp = (int*)alloc((size_t)NN*4);
  int*   degi = (int*)alloc((size_t)NN*4);
  float* ns   = (float*)alloc((size_t)NN*4);
  float* nd   = (float*)alloc((size_t)NN*4);
  u32*   gcntD = (u32*)alloc(256*4);
  u32*   gcntS = (u32*)alloc(256*4);
  u32*   bOffD = (u32*)alloc(256*4);
  float* bns  = (float*)alloc(200*4);
  float* bnq  = (float*)alloc(200*4);
  float* w2a  = (float*)alloc(400*4);
  float* cc2  = (float*)alloc(2*4);
  u16*   wt0  = (u16*)alloc((size_t)128*128*2);
  u16*   wt1  = (u16*)alloc((size_t)256*128*2);
  u16*   wt2  = (u16*)alloc((size_t)256*256*2);
  u16*   wtm1 = (u16*)alloc((size_t)256*256*2);      // padded
  // bucket scratch aliased onto zb (lifetimes disjoint), packed tightly:
  // pairD 14.45MB @0, keyS 7.2MB @15MiB -> ends 22.9MB < 38.1MB (fits, no overlap)
  u32*   pairD = (u32*)zb;
  u16*   keyS  = (u16*)((char*)zb + (size_t)15*1024*1024);

  // prep: transposes + zero counters, then binned counting sort
  k_misc<<<(16384+32768+65536+51200+512+400 + 255)/256, 256, 0, stream>>>(
      W0, W1, W2, Wm1, wt0, wt1, wt2, wtm1, gcntD, gcntS, bns, bnq);
  k_bin<<<NAB, 256, 0, stream>>>(src, dst, gcntD, gcntS, pairD, keyS);
  k_boff<<<1, 64, 0, stream>>>(gcntD, bOffD);
  k_bucket_dst<<<NBUK, 256, 0, stream>>>(pairD, gcntD, bOffD, degi, nd, rowp, csr);
  k_bucket_src<<<NBUK, 256, 0, stream>>>(keyS, gcntS, ns);

  // features * ns -> bf16
  k_cvt<<<(NN*32 + 255)/256, 256, 0, stream>>>(features, ns, X);

  int sblk = (NN + 3)/4;             // 1 wave per node
  int gblk = (NN + 127)/128;         // GEMM row blocks

  // layer 0
  k_spmm8<128><<<sblk, 256, 0, stream>>>(X, rowp, degi, csr, nd, Y);
  k_gemm8<0,128><<<dim3(1,gblk), 512, 0, stream>>>(Y, wt0, b0, ns, X, nullptr, nullptr, NN, 128);
  // layer 1
  k_spmm8<128><<<sblk, 256, 0, stream>>>(X, rowp, degi, csr, nd, Y);
  k_gemm8<0,128><<<dim3(1,gblk), 512, 0, stream>>>(Y, wt1, b1, ns, X, nullptr, nullptr, NN, 256);
  // layer 2
  k_spmm8<256><<<sblk, 256, 0, stream>>>(X, rowp, degi, csr, nd, Y);
  k_gemm8<1,256><<<dim3(1,gblk), 512, 0, stream>>>(Y, wt2, b2, nullptr, X, nullptr, nullptr, NN, 256);
  // MLP hidden: z = relu(h3 @ Wm1 + bm1) bf16 + fused BN column stats
  k_gemm8<2,256><<<dim3(1,gblk), 512, 0, stream>>>(X, wtm1, bm1, nullptr, zb, bns, bnq, NN, 200);

  // batchnorm finalize + final linear
  k_bn2<<<1, 256, 0, stream>>>(bns, bnq, gamma, beta, Wm2, bm2, w2a, cc2);
  k_final<<<sblk, 256, 0, stream>>>(zb, w2a, cc2, out);
}

// Round 11
// 752.109 us; speedup vs baseline: 1.1334x; 1.0191x over previous
//
#include <hip/hip_runtime.h>

#define NN 100000
#define NE 3200000
#define NBUK 196                  // ceil(NN/512) buckets of 512 nodes
#define CAP 18432                 // max edges per bucket (E/NBUK=16327 + slack)
#define NAB 512                   // binning blocks
#define ECHK ((NE + NAB - 1)/NAB) // 6250 edges per binning block

typedef unsigned short u16;
typedef unsigned int u32;
typedef __attribute__((ext_vector_type(8))) short short8v;
typedef __attribute__((ext_vector_type(4))) float f32x4;

__device__ __forceinline__ u16 f2b(float f){
  u32 u = __float_as_uint(f);
  u32 r = (u + 0x7fffu + ((u >> 16) & 1u)) >> 16;
  return (u16)r;
}
__device__ __forceinline__ float b2f(u16 b){
  return __uint_as_float(((u32)b) << 16);
}

// ---------------- misc: weight transposes (fp32->bf16 NxK) + zero counters -------
__global__ void k_misc(const float* __restrict__ W0, const float* __restrict__ W1,
                       const float* __restrict__ W2, const float* __restrict__ Wm1,
                       u16* __restrict__ wt0, u16* __restrict__ wt1,
                       u16* __restrict__ wt2, u16* __restrict__ wtm1,
                       u32* __restrict__ gcntD, u32* __restrict__ gcntS,
                       float* __restrict__ bns, float* __restrict__ bnq){
  int i = blockIdx.x*256 + threadIdx.x;
  if(i < 16384){
    int n = i >> 7, k = i & 127;                  // K=128,N=128
    wt0[i] = f2b(W0[k*128 + n]);
  } else if((i -= 16384) < 32768){
    int n = i >> 7, k = i & 127;                  // K=128,N=256
    wt1[i] = f2b(W1[k*256 + n]);
  } else if((i -= 32768) < 65536){
    int n = i >> 8, k = i & 255;                  // K=256,N=256
    wt2[i] = f2b(W2[k*256 + n]);
  } else if((i -= 65536) < 51200){
    int n = i >> 8, k = i & 255;                  // K=256,N=200
    wtm1[i] = f2b(Wm1[k*200 + n]);
  } else if((i -= 51200) < 512){
    if(i < 256) gcntD[i] = 0; else gcntS[i-256] = 0;
  } else if((i -= 512) < 400){
    if(i < 200) bns[i] = 0.f; else bnq[i-200] = 0.f;
  }
}

// ---------------- binning: scatter edges into node-range buckets ----------------
__global__ __launch_bounds__(256) void k_bin(const int* __restrict__ src,
                      const int* __restrict__ dst,
                      u32* __restrict__ gcntD, u32* __restrict__ gcntS,
                      u32* __restrict__ pairD, u16* __restrict__ keyS){
  __shared__ u32 cntD[NBUK], cntS[NBUK], offD[NBUK], offS[NBUK];
  int t = threadIdx.x, b = blockIdx.x;
  for(int j=t; j<NBUK; j+=256){ cntD[j]=0; cntS[j]=0; }
  __syncthreads();
  int start = b*ECHK, end = min(start + ECHK, NE);
  for(int e = start + t; e < end; e += 256){
    atomicAdd(&cntD[dst[e] >> 9], 1u);
    atomicAdd(&cntS[src[e] >> 9], 1u);
  }
  __syncthreads();
  for(int j=t; j<NBUK; j+=256){
    offD[j] = atomicAdd(&gcntD[j], cntD[j]);
    offS[j] = atomicAdd(&gcntS[j], cntS[j]);
    cntD[j] = 0; cntS[j] = 0;     // reuse as fill
  }
  __syncthreads();
  for(int e = start + t; e < end; e += 256){
    int d = dst[e], s = src[e];
    int bd = d >> 9, bs = s >> 9;
    u32 pd = offD[bd] + atomicAdd(&cntD[bd], 1u);
    u32 ps = offS[bs] + atomicAdd(&cntS[bs], 1u);
    if(pd < CAP) pairD[bd*CAP + pd] = ((u32)s << 9) | (u32)(d & 511);
    if(ps < CAP) keyS[bs*CAP + ps] = (u16)(s & 511);
  }
}

// ---------------- per-dst-bucket: bucket offset, degi, nd, rowp, CSR fill --------
__global__ __launch_bounds__(256) void k_bucket_dst(
    const u32* __restrict__ pairD, const u32* __restrict__ gcntD,
    int* __restrict__ degi,
    float* __restrict__ nd, int* __restrict__ rowp, int* __restrict__ csr){
  __shared__ u32 hist[512], excl[512], fill[512], tsum[256];
  int t = threadIdx.x, b = blockIdx.x;
  int base = b << 9;
  // bucket edge offset = sum of gcntD[0..b) via block reduction
  tsum[t] = (t < b) ? gcntD[t] : 0;
  __syncthreads();
  #pragma unroll
  for(int off=128; off>0; off>>=1){
    if(t < off) tsum[t] += tsum[t+off];
    __syncthreads();
  }
  u32 bo = tsum[0];
  __syncthreads();
  hist[t] = 0; hist[t+256] = 0; fill[t] = 0; fill[t+256] = 0;
  __syncthreads();
  int nD = gcntD[b];
  const u32* pp = pairD + (size_t)b*CAP;
  for(int i=t; i<nD; i+=256) atomicAdd(&hist[pp[i] & 511], 1u);
  __syncthreads();
  u32 a0 = hist[2*t], a1 = hist[2*t+1];
  tsum[t] = a0 + a1;
  __syncthreads();
  for(int off=1; off<256; off<<=1){
    u32 v = (t>=off) ? tsum[t-off] : 0;
    __syncthreads();
    tsum[t] += v;
    __syncthreads();
  }
  u32 texc = tsum[t] - (a0 + a1);
  excl[2*t] = texc; excl[2*t+1] = texc + a0;
  __syncthreads();
  #pragma unroll
  for(int j=0;j<2;j++){
    int local = t + j*256;
    int v = base + local;
    if(v < NN){
      int cnt = (int)hist[local];
      degi[v] = cnt + 1;                 // + self-loop
      nd[v] = rsqrtf((float)(cnt + 1));
      rowp[v] = (int)(bo + excl[local]);
    }
  }
  __syncthreads();
  for(int i=t; i<nD; i+=256){
    u32 w = pp[i];
    int local = w & 511;
    u32 pos = bo + excl[local] + atomicAdd(&fill[local], 1u);
    csr[pos] = (int)(w >> 9);
  }
}

// ---------------- per-src-bucket: ns + fused feature conversion -----------------
__global__ __launch_bounds__(256) void k_bucket_src_cvt(
    const u16* __restrict__ keyS, const u32* __restrict__ gcntS,
    const float* __restrict__ feat, float* __restrict__ ns,
    u16* __restrict__ X){
  __shared__ u32 hist[512];
  __shared__ float nsf[512];
  int t = threadIdx.x, b = blockIdx.x;
  int base = b << 9;
  hist[t] = 0; hist[t+256] = 0;
  __syncthreads();
  int nS = gcntS[b];
  const u16* kp = keyS + (size_t)b*CAP;
  for(int i=t; i<nS; i+=256) atomicAdd(&hist[kp[i]], 1u);
  __syncthreads();
  #pragma unroll
  for(int j=0;j<2;j++){
    int local = t + j*256;
    int v = base + local;
    float r = rsqrtf((float)(hist[local] + 1));
    nsf[local] = r;
    if(v < NN) ns[v] = r;
  }
  __syncthreads();
  // convert this bucket's feature rows: 512 rows x 32 float4 chunks
  for(int idx = t; idx < 512*32; idx += 256){
    int local = idx >> 5;
    int node = base + local;
    if(node >= NN) break;                 // trailing rows only in last bucket
    int c = idx & 31;                     // float4 chunk within row
    float nsv = nsf[local];
    float4 v = *(const float4*)(feat + (size_t)node*128 + c*4);
    u32 w0 = (u32)f2b(v.x*nsv) | ((u32)f2b(v.y*nsv) << 16);
    u32 w1 = (u32)f2b(v.z*nsv) | ((u32)f2b(v.w*nsv) << 16);
    *(uint2*)(X + (size_t)node*128 + c*4) = make_uint2(w0, w1);
  }
}

// ---------------- SpMM: EP=8 groups of 8 lanes, register double-buffer ----------
template<int DIM>
__global__ void k_spmm8(const u16* __restrict__ h, const int* __restrict__ rowp,
                        const int* __restrict__ degi, const int* __restrict__ csr,
                        const float* __restrict__ nd, u16* __restrict__ out){
  constexpr int EP = 8, G = 8;
  constexpr int NV = DIM/(G*8);      // uint4 per lane per row (2 or 4)
  int w = (blockIdx.x*blockDim.x + threadIdx.x) >> 6;
  int lane = threadIdx.x & 63;
  if(w >= NN) return;
  int g = lane >> 3, gl = lane & 7;
  const uint4* hv = (const uint4*)h;  // DIM/8 uint4 per row
  float acc[NV*8];
  #pragma unroll
  for(int i=0;i<NV*8;i++) acc[i]=0.f;

  int start = rowp[w];
  int vcnt = degi[w];                 // cnt + 1 (self first)

  uint4 cur[NV];
  int k = g;
  if(k < vcnt){
    int n0 = (k == 0) ? w : csr[start + k - 1];
    #pragma unroll
    for(int v4=0; v4<NV; v4++) cur[v4] = hv[(size_t)n0*(DIM/8) + gl*NV + v4];

    int kn = k + EP;
    int nn = (kn < vcnt) ? csr[start + kn - 1] : 0;   // csr prefetch

    while(true){
      bool more = (kn < vcnt);
      uint4 nxt[NV];
      if(more){
        #pragma unroll
        for(int v4=0; v4<NV; v4++) nxt[v4] = hv[(size_t)nn*(DIM/8) + gl*NV + v4];
      }
      int k2 = kn + EP;
      if(k2 < vcnt) nn = csr[start + k2 - 1];          // csr prefetch 2 ahead
      #pragma unroll
      for(int v4=0; v4<NV; v4++){
        u32 wd[4] = {cur[v4].x, cur[v4].y, cur[v4].z, cur[v4].w};
        #pragma unroll
        for(int i=0;i<4;i++){
          acc[v4*8 + 2*i]   += __uint_as_float(wd[i] << 16);
          acc[v4*8 + 2*i+1] += __uint_as_float(wd[i] & 0xffff0000u);
        }
      }
      if(!more) break;
      #pragma unroll
      for(int v4=0; v4<NV; v4++) cur[v4] = nxt[v4];
      kn = k2;
    }
  }

  #pragma unroll
  for(int i=0;i<NV*8;i++){
    acc[i] += __shfl_xor(acc[i], 8);
    acc[i] += __shfl_xor(acc[i], 16);
    acc[i] += __shfl_xor(acc[i], 32);
  }
  if(g == 0){
    float ndv = nd[w];
    #pragma unroll
    for(int v4=0; v4<NV; v4++){
      u32 o[4];
      #pragma unroll
      for(int i=0;i<4;i++){
        o[i] = (u32)f2b(acc[v4*8+2*i]*ndv) | ((u32)f2b(acc[v4*8+2*i+1]*ndv) << 16);
      }
      *(uint4*)(out + (size_t)w*DIM + (gl*NV + v4)*8) = make_uint4(o[0],o[1],o[2],o[3]);
    }
  }
}

// ---------------- 8-wave MFMA GEMM ----------------
// MREP=4: tile 128x256 (wave 64x64). MREP=2: tile 128x128 (wave 32x64).
// OUTMODE 0: bf16 out * ns[row]; 1: bf16 out; 2: bf16 out + BN col sums.
template<int OUTMODE, int KK, int MREP>
__global__ __launch_bounds__(512) void k_gemm8(
    const u16* __restrict__ A, const u16* __restrict__ Bt,
    const float* __restrict__ bias, const float* __restrict__ ns,
    u16* __restrict__ outb,
    float* __restrict__ bns, float* __restrict__ bnq,
    int M, int Nn)
{
  __shared__ u16 As[128*32];
  __shared__ u16 Bs[256*32];
  int t = threadIdx.x;
  int wave = t >> 6, lane = t & 63;
  int l15 = lane & 15, l4 = lane >> 4;
  int wr, wc;
  if(MREP == 4){ wr = (wave >> 2)*64; wc = (wave & 3)*64; }
  else         { wr = (wave >> 1)*32; wc = (wave & 1)*64; }
  int row0 = blockIdx.y*128;

  f32x4 acc[MREP][4];
  #pragma unroll
  for(int m=0;m<MREP;m++)
    #pragma unroll
    for(int n=0;n<4;n++) acc[m][n] = (f32x4)(0.f);

  // staging maps
  int ar = t >> 2, ac = t & 3;             // A: 4 threads/row, 1 chunk each
  int swA = (ar >> 1) & 3;
  int br = t >> 1, bc0 = (t & 1)*2;        // B: 2 threads/row, 2 chunks each
  int swB = (br >> 1) & 3;
  bool avalid = (row0 + ar) < M;
  bool bvalid = br < Nn;
  const u16* Ap = A  + (size_t)(row0 + ar)*KK + ac*8;
  const u16* Bp = Bt + (size_t)br*KK + bc0*8;

  #pragma unroll
  for(int k0 = 0; k0 < KK; k0 += 32){
    uint4 va = make_uint4(0,0,0,0), vb0 = va, vb1 = va;
    if(avalid) va = *(const uint4*)(Ap + k0);
    if(bvalid){ vb0 = *(const uint4*)(Bp + k0); vb1 = *(const uint4*)(Bp + k0 + 8); }
    __syncthreads();
    *(uint4*)&As[ar*32 + (ac ^ swA)*8] = va;
    *(uint4*)&Bs[br*32 + (bc0 ^ swB)*8] = vb0;
    *(uint4*)&Bs[br*32 + ((bc0+1) ^ swB)*8] = vb1;
    __syncthreads();

    short8v af[MREP], bg[4];
    #pragma unroll
    for(int m=0;m<MREP;m++){
      int r = wr + m*16 + l15;
      int kc = l4 ^ ((r >> 1) & 3);
      af[m] = *(const short8v*)&As[r*32 + kc*8];
    }
    #pragma unroll
    for(int n=0;n<4;n++){
      int r = wc + n*16 + l15;
      int kc = l4 ^ ((r >> 1) & 3);
      bg[n] = *(const short8v*)&Bs[r*32 + kc*8];
    }
    #pragma unroll
    for(int m=0;m<MREP;m++)
      #pragma unroll
      for(int n=0;n<4;n++)
        acc[m][n] = __builtin_amdgcn_mfma_f32_16x16x32_bf16(af[m], bg[n], acc[m][n], 0, 0, 0);
  }

  float nsv[MREP][4];
  if(OUTMODE == 0){
    #pragma unroll
    for(int m=0;m<MREP;m++)
      #pragma unroll
      for(int r=0;r<4;r++){
        int gr = row0 + wr + m*16 + l4*4 + r;
        nsv[m][r] = (gr < M) ? ns[gr] : 0.f;
      }
  }
  #pragma unroll
  for(int n=0;n<4;n++){
    int gc = wc + n*16 + l15;
    float bv = (gc < Nn) ? bias[gc] : 0.f;
    float s = 0.f, q = 0.f;
    #pragma unroll
    for(int m=0;m<MREP;m++){
      #pragma unroll
      for(int r=0;r<4;r++){
        int gr = row0 + wr + m*16 + l4*4 + r;
        bool ok = (gr < M) && (gc < Nn);
        float v = ok ? fmaxf(acc[m][n][r] + bv, 0.f) : 0.f;
        if(ok){
          if(OUTMODE == 0) outb[(size_t)gr*Nn + gc] = f2b(v * nsv[m][r]);
          else             outb[(size_t)gr*Nn + gc] = f2b(v);
        }
        if(OUTMODE == 2){ s += v; q += v*v; }
      }
    }
    if(OUTMODE == 2){
      s += __shfl_xor(s, 16); s += __shfl_xor(s, 32);
      q += __shfl_xor(q, 16); q += __shfl_xor(q, 32);
      if(l4 == 0 && gc < Nn){ atomicAdd(&bns[gc], s); atomicAdd(&bnq[gc], q); }
    }
  }
}

// ---------------- batchnorm finalize + fused final linear ----------------
__global__ void k_bn2(const float* __restrict__ bns, const float* __restrict__ bnq,
                      const float* __restrict__ gamma, const float* __restrict__ beta,
                      const float* __restrict__ Wm2, const float* __restrict__ bm2,
                      float* __restrict__ w2a, float* __restrict__ cc2){
  __shared__ float c0s[200];
  int t = threadIdx.x;
  if(t<200){
    float mu  = bns[t] * (1.0f/NN);
    float var = bnq[t] * (1.0f/NN) - mu*mu;
    float a   = rsqrtf(var + 1e-5f) * gamma[t];
    w2a[t*2+0] = a*Wm2[t*2+0];
    w2a[t*2+1] = a*Wm2[t*2+1];
    c0s[t] = beta[t] - mu*a;
  }
  __syncthreads();
  if(t<2){
    float cst = bm2[t];
    for(int k=0;k<200;k++) cst += c0s[k]*Wm2[k*2+t];
    cc2[t] = cst;
  }
}

// z is bf16 rows of 200 (100 u32 words)
__global__ void k_final(const u16* __restrict__ z, const float* __restrict__ w2a,
                        const float* __restrict__ cc2, float* __restrict__ out){
  int lane = threadIdx.x & 63;
  int gw = (blockIdx.x*blockDim.x + threadIdx.x) >> 6;
  if(gw >= NN) return;
  const u32* zr = (const u32*)(z + (size_t)gw*200);
  float p0=0.f, p1=0.f;
  #pragma unroll
  for(int i=0;i<2;i++){
    int wd = lane + i*64;
    if(wd < 100){
      u32 v = zr[wd];
      float x0 = __uint_as_float(v << 16);
      float x1 = __uint_as_float(v & 0xffff0000u);
      int e = wd*2;
      p0 += x0*w2a[e*2+0] + x1*w2a[e*2+2];
      p1 += x0*w2a[e*2+1] + x1*w2a[e*2+3];
    }
  }
  for(int off=32; off>0; off>>=1){
    p0 += __shfl_down(p0, off);
    p1 += __shfl_down(p1, off);
  }
  if(lane==0){ out[gw*2+0] = p0 + cc2[0]; out[gw*2+1] = p1 + cc2[1]; }
}

// ---------------- launch ----------------
extern "C" void kernel_launch(void* const* d_in, const int* in_sizes, int n_in,
                              void* d_out, int out_size, void* d_ws, size_t ws_size,
                              hipStream_t stream) {
  const float* features = (const float*)d_in[0];
  const int*   src = (const int*)d_in[1];
  const int*   dst = (const int*)d_in[2];
  const float* W0  = (const float*)d_in[3];
  const float* b0  = (const float*)d_in[4];
  const float* W1  = (const float*)d_in[5];
  const float* b1  = (const float*)d_in[6];
  const float* W2  = (const float*)d_in[7];
  const float* b2  = (const float*)d_in[8];
  const float* Wm1 = (const float*)d_in[9];
  const float* bm1 = (const float*)d_in[10];
  const float* gamma = (const float*)d_in[11];
  const float* beta  = (const float*)d_in[12];
  const float* Wm2 = (const float*)d_in[13];
  const float* bm2 = (const float*)d_in[14];
  float* out = (float*)d_out;

  char* p = (char*)d_ws;
  auto alloc = [&](size_t bytes)->void*{
    void* r = (void*)p; p += (bytes + 255) & ~(size_t)255; return r;
  };
  u16*   X    = (u16*)alloc((size_t)NN*256*2);
  u16*   Y    = (u16*)alloc((size_t)NN*256*2);
  u16*   zb   = (u16*)alloc((size_t)NN*200*2);       // 38.1 MB bf16 z, dead until MLP GEMM
  int*   csr  = (int*)alloc((size_t)NE*4);
  int*   rowp = (int*)alloc((size_t)NN*4);
  int*   degi = (int*)alloc((size_t)NN*4);
  float* ns   = (float*)alloc((size_t)NN*4);
  float* nd   = (float*)alloc((size_t)NN*4);
  u32*   gcntD = (u32*)alloc(256*4);
  u32*   gcntS = (u32*)alloc(256*4);
  float* bns  = (float*)alloc(200*4);
  float* bnq  = (float*)alloc(200*4);
  float* w2a  = (float*)alloc(400*4);
  float* cc2  = (float*)alloc(2*4);
  u16*   wt0  = (u16*)alloc((size_t)128*128*2);
  u16*   wt1  = (u16*)alloc((size_t)256*128*2);
  u16*   wt2  = (u16*)alloc((size_t)256*256*2);
  u16*   wtm1 = (u16*)alloc((size_t)256*256*2);      // padded
  // bucket scratch aliased onto zb (lifetimes disjoint), packed tightly:
  // pairD 14.45MB @0, keyS 7.2MB @15MiB -> ends 22.9MB < 38.1MB (fits, no overlap)
  u32*   pairD = (u32*)zb;
  u16*   keyS  = (u16*)((char*)zb + (size_t)15*1024*1024);

  // prep: transposes + zero counters, then binned counting sort
  k_misc<<<(16384+32768+65536+51200+512+400 + 255)/256, 256, 0, stream>>>(
      W0, W1, W2, Wm1, wt0, wt1, wt2, wtm1, gcntD, gcntS, bns, bnq);
  k_bin<<<NAB, 256, 0, stream>>>(src, dst, gcntD, gcntS, pairD, keyS);
  k_bucket_dst<<<NBUK, 256, 0, stream>>>(pairD, gcntD, degi, nd, rowp, csr);
  k_bucket_src_cvt<<<NBUK, 256, 0, stream>>>(keyS, gcntS, features, ns, X);

  int sblk = (NN + 3)/4;             // 1 wave per node
  int gblk = (NN + 127)/128;         // GEMM row blocks

  // layer 0 (N=128: half-tile MREP=2)
  k_spmm8<128><<<sblk, 256, 0, stream>>>(X, rowp, degi, csr, nd, Y);
  k_gemm8<0,128,2><<<dim3(1,gblk), 512, 0, stream>>>(Y, wt0, b0, ns, X, nullptr, nullptr, NN, 128);
  // layer 1
  k_spmm8<128><<<sblk, 256, 0, stream>>>(X, rowp, degi, csr, nd, Y);
  k_gemm8<0,128,4><<<dim3(1,gblk), 512, 0, stream>>>(Y, wt1, b1, ns, X, nullptr, nullptr, NN, 256);
  // layer 2
  k_spmm8<256><<<sblk, 256, 0, stream>>>(X, rowp, degi, csr, nd, Y);
  k_gemm8<1,256,4><<<dim3(1,gblk), 512, 0, stream>>>(Y, wt2, b2, nullptr, X, nullptr, nullptr, NN, 256);
  // MLP hidden: z = relu(h3 @ Wm1 + bm1) bf16 + fused BN column stats
  k_gemm8<2,256,4><<<dim3(1,gblk), 512, 0, stream>>>(X, wtm1, bm1, nullptr, zb, bns, bnq, NN, 200);

  // batchnorm finalize + final linear
  k_bn2<<<1, 256, 0, stream>>>(bns, bnq, gamma, beta, Wm2, bm2, w2a, cc2);
  k_final<<<sblk, 256, 0, stream>>>(zb, w2a, cc2, out);
}